// Round 1
// baseline (1268.833 us; speedup 1.0000x reference)
//
#include <hip/hip_runtime.h>

// QuestionSpecificMLP: fused trunk (2-layer MLP) + per-sample routed head.
// B=131072, D_IN=385, D_H=192, Q=1000, C=16. All fp32 this round (correctness
// baseline); trunk GEMMs are the target for bf16 MFMA in later rounds.

namespace {
constexpr int kB   = 131072;
constexpr int kDin = 385;
constexpr int kDh  = 192;
constexpr int kQ   = 1000;
constexpr int kC   = 16;

constexpr int BM = 64;   // rows per block
constexpr int BK = 16;   // K-chunk
constexpr int NT = 256;  // threads per block
}

__global__ __launch_bounds__(NT, 2)
void fused_qmlp(const float* __restrict__ x,
                const int*   __restrict__ qid,
                const int*   __restrict__ isc,
                const float* __restrict__ W1,
                const float* __restrict__ b1,
                const float* __restrict__ W2,
                const float* __restrict__ b2,
                const float* __restrict__ Wh,
                const float* __restrict__ bh,
                float* __restrict__ out)
{
    // LDS budget: 4K + 12K + 48K = 64 KB exactly -> 2 blocks/CU (160 KB LDS).
    __shared__ __align__(16) float xs[BK][BM];    // x tile, transposed [k][row]
    __shared__ __align__(16) float ws[BK][kDh];   // weight K-chunk [k][col]
    __shared__ __align__(16) float hs[kDh][BM];   // h transposed [k][row]; later aliased as feat[BM][kDh]

    const int tid = threadIdx.x;
    const int tx  = tid & 15;   // col group 0..15 (12 cols each)
    const int ty  = tid >> 4;   // row group 0..15 (4 rows each)
    const int row0 = blockIdx.x * BM;

    float acc[4][12];
    #pragma unroll
    for (int i = 0; i < 4; ++i)
        #pragma unroll
        for (int j = 0; j < 12; ++j) acc[i][j] = 0.f;

    // ---------------- layer 1: h = relu(x @ W1 + b1) ----------------
    for (int k0 = 0; k0 < kDin; k0 += BK) {   // 25 iterations (last has 1 valid k)
        #pragma unroll
        for (int i = 0; i < 4; ++i) {         // 64x16 x-tile, transposed into LDS
            int lin = tid + i * NT;           // 0..1023
            int r   = lin >> 4;
            int kk  = lin & 15;
            int gk  = k0 + kk;
            xs[kk][r] = (gk < kDin) ? x[(size_t)(row0 + r) * kDin + gk] : 0.f;
        }
        #pragma unroll
        for (int i = 0; i < 12; ++i) {        // 16x192 W1 chunk
            int lin = tid + i * NT;           // 0..3071
            int kk  = lin / kDh;
            int col = lin - kk * kDh;
            int gk  = k0 + kk;
            ws[kk][col] = (gk < kDin) ? W1[(size_t)gk * kDh + col] : 0.f;
        }
        __syncthreads();
        #pragma unroll
        for (int kk = 0; kk < BK; ++kk) {
            float4 av  = *(const float4*)&xs[kk][ty * 4];
            float4 bv0 = *(const float4*)&ws[kk][tx * 12 + 0];
            float4 bv1 = *(const float4*)&ws[kk][tx * 12 + 4];
            float4 bv2 = *(const float4*)&ws[kk][tx * 12 + 8];
            float a[4]  = {av.x, av.y, av.z, av.w};
            float b[12] = {bv0.x, bv0.y, bv0.z, bv0.w,
                           bv1.x, bv1.y, bv1.z, bv1.w,
                           bv2.x, bv2.y, bv2.z, bv2.w};
            #pragma unroll
            for (int i = 0; i < 4; ++i)
                #pragma unroll
                for (int j = 0; j < 12; ++j)
                    acc[i][j] = fmaf(a[i], b[j], acc[i][j]);
        }
        __syncthreads();
    }

    // bias + relu -> hs (transposed), reset acc for layer 2
    #pragma unroll
    for (int j = 0; j < 12; ++j) {
        int col = tx * 12 + j;
        float bb = b1[col];
        #pragma unroll
        for (int i = 0; i < 4; ++i) {
            float v = acc[i][j] + bb;
            hs[col][ty * 4 + i] = v > 0.f ? v : 0.f;
            acc[i][j] = 0.f;
        }
    }
    __syncthreads();

    // ---------------- layer 2: feat = relu(h @ W2 + b2) ----------------
    for (int k0 = 0; k0 < kDh; k0 += BK) {    // 12 iterations
        #pragma unroll
        for (int i = 0; i < 12; ++i) {
            int lin = tid + i * NT;
            int kk  = lin / kDh;
            int col = lin - kk * kDh;
            ws[kk][col] = W2[(size_t)(k0 + kk) * kDh + col];
        }
        __syncthreads();
        #pragma unroll
        for (int kk = 0; kk < BK; ++kk) {
            float4 av  = *(const float4*)&hs[k0 + kk][ty * 4];
            float4 bv0 = *(const float4*)&ws[kk][tx * 12 + 0];
            float4 bv1 = *(const float4*)&ws[kk][tx * 12 + 4];
            float4 bv2 = *(const float4*)&ws[kk][tx * 12 + 8];
            float a[4]  = {av.x, av.y, av.z, av.w};
            float b[12] = {bv0.x, bv0.y, bv0.z, bv0.w,
                           bv1.x, bv1.y, bv1.z, bv1.w,
                           bv2.x, bv2.y, bv2.z, bv2.w};
            #pragma unroll
            for (int i = 0; i < 4; ++i)
                #pragma unroll
                for (int j = 0; j < 12; ++j)
                    acc[i][j] = fmaf(a[i], b[j], acc[i][j]);
        }
        __syncthreads();
    }

    // bias + relu -> feat, row-major, aliasing the (now dead) hs region.
    float* fs = &hs[0][0];                    // [BM][kDh] row-major
    #pragma unroll
    for (int j = 0; j < 12; ++j) {
        int col = tx * 12 + j;
        float bb = b2[col];
        #pragma unroll
        for (int i = 0; i < 4; ++i) {
            float v = acc[i][j] + bb;
            fs[(ty * 4 + i) * kDh + col] = v > 0.f ? v : 0.f;
        }
    }
    __syncthreads();

    // ---------------- routed head: logits = Wq @ feat + bq ----------------
    // One wave handles 16 rows; within a wave: lane = 4*class + quarter.
    const int lane  = tid & 63;
    const int wave  = tid >> 6;     // 0..3
    const int cls   = lane >> 2;    // 0..15
    const int qpart = lane & 3;     // 0..3, each covers 48 of the 192 dims

    #pragma unroll 1
    for (int rr = 0; rr < 16; ++rr) {
        int row  = wave * 16 + rr;
        int grow = row0 + row;
        int hidx = qid[grow] + isc[grow] * kQ;      // wave-uniform per row
        const float4* wp = (const float4*)(Wh + ((size_t)hidx * kC + cls) * kDh + qpart * 48);
        const float4* fp = (const float4*)(fs + row * kDh + qpart * 48);
        float s = 0.f;
        #pragma unroll
        for (int t = 0; t < 12; ++t) {
            float4 w = wp[t];
            float4 f = fp[t];
            s += w.x * f.x + w.y * f.y + w.z * f.z + w.w * f.w;
        }
        s += __shfl_xor(s, 1);
        s += __shfl_xor(s, 2);
        if (qpart == 0)
            out[(size_t)grow * kC + cls] = s + bh[hidx * kC + cls];
    }
}

extern "C" void kernel_launch(void* const* d_in, const int* in_sizes, int n_in,
                              void* d_out, int out_size, void* d_ws, size_t ws_size,
                              hipStream_t stream) {
    const float* x   = (const float*)d_in[0];
    const int*   qd  = (const int*)  d_in[1];
    const int*   ic  = (const int*)  d_in[2];
    const float* W1  = (const float*)d_in[3];
    const float* b1  = (const float*)d_in[4];
    const float* W2  = (const float*)d_in[5];
    const float* b2  = (const float*)d_in[6];
    const float* Wh  = (const float*)d_in[7];
    const float* bh  = (const float*)d_in[8];
    float* out = (float*)d_out;

    dim3 grid(kB / BM);   // 2048 blocks
    dim3 block(NT);
    hipLaunchKernelGGL(fused_qmlp, grid, block, 0, stream,
                       x, qd, ic, W1, b1, W2, b2, Wh, bh, out);
}

// Round 2
// 530.102 us; speedup vs baseline: 2.3936x; 2.3936x over previous
//
#include <hip/hip_runtime.h>
#include <stdint.h>
#include <stddef.h>

// QuestionSpecificMLP: bf16-MFMA trunk (2-layer MLP) + fp32 routed head.
// Trunk uses v_mfma_f32_16x16x32_bf16 with pre-swizzled weights in d_ws.
// Verified layouts (learn_hip m89/m91): A[m=lane&15][k=quad*8+j],
// B[k=quad*8+j][n=lane&15], D[row=quad*4+reg][col=lane&15].

typedef short s8v __attribute__((ext_vector_type(8)));   // 8 bf16 (4 VGPRs)
typedef float f4v __attribute__((ext_vector_type(4)));   // MFMA acc

namespace {
constexpr int kDin = 385;
constexpr int kDh  = 192;
constexpr int kQ   = 1000;
constexpr int kC   = 16;
constexpr int BM   = 64;    // rows per block
constexpr int NT   = 256;   // 4 waves
constexpr int NK1  = 13;    // ceil(385/32) k-steps, layer 1 (padded with zeros)
constexpr int NK2  = 6;     // 192/32 k-steps, layer 2
constexpr int CHUNK = 12 * 64 * 8;            // bf16 elems per swizzled k-chunk (6144)
constexpr size_t W2_OFF_BYTES = 160 * 1024;   // W1sw = 159744 B fits below

// LDS layout (bytes). feat (fp32) reuses [0, 50176) after layer 2.
constexpr int H_STRIDE = 208;   // bf16/row for h   (64*208*2 = 26624 B)
constexpr int F_STRIDE = 196;   // fp32/row for feat (64*196*4 = 50176 B)
constexpr int X_STRIDE = 40;    // bf16/row for x k-chunk
constexpr int LDS_H   = 0;
constexpr int LDS_B   = 26624;              // +12288 -> 38912
constexpr int LDS_X   = 38912;              // +5120  -> 44032
constexpr int LDS_IDX = 50176;              // 64 ints
constexpr int LDS_SZ  = 50176 + 256;        // 50432 B -> 3 blocks/CU
}

__device__ __forceinline__ unsigned short f2bf(float f) {
  unsigned int u = __float_as_uint(f);
  u = u + 0x7fffu + ((u >> 16) & 1u);       // RNE (non-NaN inputs)
  return (unsigned short)(u >> 16);
}

// Swizzle W[K x 192] fp32 row-major -> bf16 B-fragment order:
// out[kk*6144 + (t*64 + l)*8 + j] = W[kk*32 + (l>>4)*8 + j][t*16 + (l&15)], 0 if k>=K
__global__ void prep_swizzle(const float* __restrict__ W, int K, int NKS,
                             unsigned short* __restrict__ out) {
  int idx = blockIdx.x * blockDim.x + threadIdx.x;
  int total = NKS * CHUNK;
  if (idx >= total) return;
  int j  = idx & 7;
  int l  = (idx >> 3) & 63;
  int rem = idx % CHUNK;
  int t  = rem >> 9;            // 512 elems per col-tile
  int kk = idx / CHUNK;
  int k  = kk * 32 + ((l >> 4) << 3) + j;
  int c  = t * 16 + (l & 15);
  float v = (k < K) ? W[(size_t)k * kDh + c] : 0.f;
  out[idx] = f2bf(v);
}

__global__ __launch_bounds__(NT)
void fused_qmlp2(const float* __restrict__ x,
                 const int*   __restrict__ qid,
                 const int*   __restrict__ isc,
                 const float* __restrict__ b1,
                 const float* __restrict__ b2,
                 const float* __restrict__ Wh,
                 const float* __restrict__ bh,
                 const unsigned short* __restrict__ W1sw,
                 const unsigned short* __restrict__ W2sw,
                 float* __restrict__ out) {
  __shared__ __align__(16) char smem[LDS_SZ];
  unsigned short* hS  = (unsigned short*)(smem + LDS_H);
  unsigned short* bS  = (unsigned short*)(smem + LDS_B);
  unsigned short* xS  = (unsigned short*)(smem + LDS_X);
  float*          fS  = (float*)smem;             // aliases hS/bS/xS (phase-ordered)
  int*            idxS = (int*)(smem + LDS_IDX);

  const int tid  = threadIdx.x;
  const int lane = tid & 63, wid = tid >> 6;
  const int m = lane & 15, quad = lane >> 4;
  const int rh = wid & 1;        // row half: 32 rows
  const int ch = wid >> 1;       // col half: 96 cols = 6 tiles
  const int row0 = blockIdx.x * BM;

  if (tid < BM) {
    int g = row0 + tid;
    idxS[tid] = qid[g] + isc[g] * kQ;   // wave-routed head index, hoisted early
  }

  f4v acc0[6], acc1[6];
  #pragma unroll
  for (int t = 0; t < 6; ++t) {
    acc0[t] = (f4v){0.f, 0.f, 0.f, 0.f};
    acc1[t] = (f4v){0.f, 0.f, 0.f, 0.f};
  }

  // ---------------- layer 1: h = relu(x @ W1 + b1), K padded to 416 ----------
  for (int kk = 0; kk < NK1; ++kk) {
    #pragma unroll
    for (int i = 0; i < 8; ++i) {                 // stage x 64x32 chunk -> bf16
      int lin = tid + i * NT;
      int r = lin >> 5, c = lin & 31;
      int gk = kk * 32 + c;
      float v = (gk < kDin) ? x[(size_t)(row0 + r) * kDin + gk] : 0.f;
      xS[r * X_STRIDE + c] = f2bf(v);
    }
    const s8v* src = (const s8v*)(W1sw + (size_t)kk * CHUNK);
    #pragma unroll
    for (int i = 0; i < 3; ++i)                   // stage swizzled W1 chunk (12 KB)
      ((s8v*)bS)[i * NT + tid] = src[i * NT + tid];
    __syncthreads();

    const int ab = (rh * 32 + m) * X_STRIDE + quad * 8;
    s8v a0 = *(const s8v*)&xS[ab];
    s8v a1 = *(const s8v*)&xS[ab + 16 * X_STRIDE];
    #pragma unroll
    for (int t = 0; t < 6; ++t) {
      s8v b = *(const s8v*)&bS[((ch * 6 + t) * 64 + lane) * 8];
      acc0[t] = __builtin_amdgcn_mfma_f32_16x16x32_bf16(a0, b, acc0[t], 0, 0, 0);
      acc1[t] = __builtin_amdgcn_mfma_f32_16x16x32_bf16(a1, b, acc1[t], 0, 0, 0);
    }
    __syncthreads();
  }

  // epilogue 1: bias+relu, h -> LDS row-major bf16 (A-operand friendly)
  #pragma unroll
  for (int t = 0; t < 6; ++t) {
    int c = ch * 96 + t * 16 + m;
    float bb = b1[c];
    #pragma unroll
    for (int r4 = 0; r4 < 4; ++r4) {
      int r = rh * 32 + quad * 4 + r4;
      float v0 = acc0[t][r4] + bb; v0 = v0 > 0.f ? v0 : 0.f;
      hS[r * H_STRIDE + c] = f2bf(v0);
      float v1 = acc1[t][r4] + bb; v1 = v1 > 0.f ? v1 : 0.f;
      hS[(r + 16) * H_STRIDE + c] = f2bf(v1);
      acc0[t][r4] = 0.f;
      acc1[t][r4] = 0.f;
    }
  }

  // ---------------- layer 2: feat = relu(h @ W2 + b2) ----------------
  for (int kk = 0; kk < NK2; ++kk) {
    const s8v* src = (const s8v*)(W2sw + (size_t)kk * CHUNK);
    #pragma unroll
    for (int i = 0; i < 3; ++i)
      ((s8v*)bS)[i * NT + tid] = src[i * NT + tid];
    __syncthreads();                               // also fences epilogue-1 hS writes

    const int ab = (rh * 32 + m) * H_STRIDE + kk * 32 + quad * 8;
    s8v a0 = *(const s8v*)&hS[ab];
    s8v a1 = *(const s8v*)&hS[ab + 16 * H_STRIDE];
    #pragma unroll
    for (int t = 0; t < 6; ++t) {
      s8v b = *(const s8v*)&bS[((ch * 6 + t) * 64 + lane) * 8];
      acc0[t] = __builtin_amdgcn_mfma_f32_16x16x32_bf16(a0, b, acc0[t], 0, 0, 0);
      acc1[t] = __builtin_amdgcn_mfma_f32_16x16x32_bf16(a1, b, acc1[t], 0, 0, 0);
    }
    __syncthreads();
  }

  // epilogue 2: bias+relu, feat -> LDS fp32 (reuses h/B/x regions; all dead)
  #pragma unroll
  for (int t = 0; t < 6; ++t) {
    int c = ch * 96 + t * 16 + m;
    float bb = b2[c];
    #pragma unroll
    for (int r4 = 0; r4 < 4; ++r4) {
      int r = rh * 32 + quad * 4 + r4;
      float v0 = acc0[t][r4] + bb;
      fS[r * F_STRIDE + c] = v0 > 0.f ? v0 : 0.f;
      float v1 = acc1[t][r4] + bb;
      fS[(r + 16) * F_STRIDE + c] = v1 > 0.f ? v1 : 0.f;
    }
  }
  __syncthreads();

  // ---------------- routed head (fp32): logits = Wq @ feat + bq --------------
  const int cls = lane >> 2, qp = lane & 3;        // 16 classes x 4 k-quarters
  #pragma unroll 2
  for (int rr = 0; rr < 16; ++rr) {
    int row = wid * 16 + rr;
    int hidx = idxS[row];
    const f4v* wp = (const f4v*)(Wh + ((size_t)hidx * kC + cls) * kDh + qp * 48);
    const f4v* fp = (const f4v*)(fS + row * F_STRIDE + qp * 48);
    float s = 0.f;
    #pragma unroll
    for (int t = 0; t < 12; ++t) {
      f4v w = wp[t], f = fp[t];
      s += w[0] * f[0] + w[1] * f[1] + w[2] * f[2] + w[3] * f[3];
    }
    s += __shfl_xor(s, 1);
    s += __shfl_xor(s, 2);
    if (qp == 0)
      out[(size_t)(row0 + row) * kC + cls] = s + bh[(size_t)hidx * kC + cls];
  }
}

extern "C" void kernel_launch(void* const* d_in, const int* in_sizes, int n_in,
                              void* d_out, int out_size, void* d_ws, size_t ws_size,
                              hipStream_t stream) {
  const float* x  = (const float*)d_in[0];
  const int*   qd = (const int*)  d_in[1];
  const int*   ic = (const int*)  d_in[2];
  const float* W1 = (const float*)d_in[3];
  const float* b1 = (const float*)d_in[4];
  const float* W2 = (const float*)d_in[5];
  const float* b2 = (const float*)d_in[6];
  const float* Wh = (const float*)d_in[7];
  const float* bh = (const float*)d_in[8];
  float* out = (float*)d_out;

  unsigned short* W1sw = (unsigned short*)d_ws;
  unsigned short* W2sw = (unsigned short*)((char*)d_ws + W2_OFF_BYTES);

  prep_swizzle<<<(NK1 * CHUNK + 255) / 256, 256, 0, stream>>>(W1, kDin, NK1, W1sw);
  prep_swizzle<<<(NK2 * CHUNK + 255) / 256, 256, 0, stream>>>(W2, kDh,  NK2, W2sw);

  int B = in_sizes[1];                 // 131072
  fused_qmlp2<<<B / BM, NT, 0, stream>>>(x, qd, ic, b1, b2, Wh, bh, W1sw, W2sw, out);
}

// Round 3
// 476.090 us; speedup vs baseline: 2.6651x; 1.1134x over previous
//
#include <hip/hip_runtime.h>
#include <stdint.h>
#include <stddef.h>

// QuestionSpecificMLP: counting-sort by routed head index, then fused
// bf16-MFMA trunk + fp32 routed head. Sorting makes each 64-row block touch
// ~1-2 distinct heads (vs ~60 random), cutting head-bank HBM refetch ~25x.

typedef short s8v __attribute__((ext_vector_type(8)));   // 8 bf16 (4 VGPRs)
typedef float f4v __attribute__((ext_vector_type(4)));   // MFMA acc
typedef float f4a __attribute__((ext_vector_type(4), aligned(4)));  // unaligned-ok float4

namespace {
constexpr int kDin = 385;
constexpr int kDh  = 192;
constexpr int kQ   = 1000;
constexpr int kC   = 16;
constexpr int kH   = 2 * kQ;      // 2000 head slots
constexpr int BM   = 64;
constexpr int NT   = 256;
constexpr int NK1  = 13;          // ceil(385/32), zero-padded
constexpr int NK2  = 6;           // 192/32
constexpr int CHUNK = 12 * 64 * 8;   // 6144 bf16 per swizzled k-chunk
constexpr int H2   = 200;         // bf16 stride for h / feat rows

// workspace layout (bytes)
constexpr size_t WS_W1   = 0;        // 159744
constexpr size_t WS_W2   = 163840;   // 73728
constexpr size_t WS_HIST = 245760;   // 2048*4
constexpr size_t WS_CUR  = 253952;   // 2048*4
constexpr size_t WS_PERM = 262144;   // 131072*4 -> ends at 768 KB
}

__device__ __forceinline__ unsigned short f2bf(float f) {
  unsigned int u = __float_as_uint(f);
  u = u + 0x7fffu + ((u >> 16) & 1u);       // RNE (non-NaN inputs)
  return (unsigned short)(u >> 16);
}
__device__ __forceinline__ float bf2f(short h) {
  return __uint_as_float(((unsigned int)(unsigned short)h) << 16);
}

// ---- sort pipeline -------------------------------------------------------
__global__ void zero_hist(int* hist) {
  int i = blockIdx.x * blockDim.x + threadIdx.x;
  if (i < 2048) hist[i] = 0;
}
__global__ void hist_k(const int* __restrict__ qid, const int* __restrict__ isc,
                       int B, int* __restrict__ hist) {
  int i = blockIdx.x * blockDim.x + threadIdx.x;
  if (i < B) atomicAdd(&hist[qid[i] + isc[i] * kQ], 1);
}
__global__ void scan_k(const int* __restrict__ hist, int* __restrict__ cursor) {
  __shared__ int s[2048];
  int t = threadIdx.x;
  s[t] = hist[t]; s[t + 1024] = hist[t + 1024];
  __syncthreads();
  for (int d = 1; d < 2048; d <<= 1) {
    int a0 = (t >= d) ? s[t - d] : 0;
    int a1 = (t + 1024 >= d) ? s[t + 1024 - d] : 0;
    __syncthreads();
    s[t] += a0; s[t + 1024] += a1;
    __syncthreads();
  }
  cursor[t] = s[t] - hist[t];                       // exclusive prefix
  cursor[t + 1024] = s[t + 1024] - hist[t + 1024];
}
__global__ void scatter_k(const int* __restrict__ qid, const int* __restrict__ isc,
                          int B, int* __restrict__ cursor, int* __restrict__ perm) {
  int i = blockIdx.x * blockDim.x + threadIdx.x;
  if (i < B) {
    int h = qid[i] + isc[i] * kQ;
    int pos = atomicAdd(&cursor[h], 1);
    perm[pos] = i;
  }
}

// ---- weight pre-swizzle (B-fragment order, verified R2) ------------------
__global__ void prep_swizzle(const float* __restrict__ W, int K, int NKS,
                             unsigned short* __restrict__ out) {
  int idx = blockIdx.x * blockDim.x + threadIdx.x;
  int total = NKS * CHUNK;
  if (idx >= total) return;
  int j  = idx & 7;
  int l  = (idx >> 3) & 63;
  int rem = idx % CHUNK;
  int t  = rem >> 9;
  int kk = idx / CHUNK;
  int k  = kk * 32 + ((l >> 4) << 3) + j;
  int c  = t * 16 + (l & 15);
  float v = (k < K) ? W[(size_t)k * kDh + c] : 0.f;
  out[idx] = f2bf(v);
}

// ---- main fused kernel ---------------------------------------------------
__global__ __launch_bounds__(NT, 4)
void fused_qmlp3(const float* __restrict__ x,
                 const int*   __restrict__ qid,
                 const int*   __restrict__ isc,
                 const float* __restrict__ b1,
                 const float* __restrict__ b2,
                 const float* __restrict__ Wh,
                 const float* __restrict__ bh,
                 const unsigned short* __restrict__ W1sw,
                 const unsigned short* __restrict__ W2sw,
                 const int*   __restrict__ perm,
                 float* __restrict__ out) {
  __shared__ __align__(16) unsigned short hS[BM * H2];  // 25600 B; h then feat
  __shared__ __align__(16) unsigned short bS[CHUNK];    // 12288 B
  __shared__ int permS[BM];
  __shared__ int idxS[BM];

  const int tid  = threadIdx.x;
  const int lane = tid & 63, wid = tid >> 6;
  const int m = lane & 15, quad = lane >> 4;
  const int rh = wid & 1, ch = wid >> 1;
  const int row0 = blockIdx.x * BM;

  if (tid < BM) {
    int p = perm[row0 + tid];
    permS[tid] = p;
    idxS[tid] = qid[p] + isc[p] * kQ;
  }
  __syncthreads();

  const size_t xr0 = (size_t)permS[rh * 32 + m] * kDin;
  const size_t xr1 = (size_t)permS[rh * 32 + m + 16] * kDin;

  f4v acc0[6], acc1[6];
  #pragma unroll
  for (int t = 0; t < 6; ++t) {
    acc0[t] = (f4v){0.f, 0.f, 0.f, 0.f};
    acc1[t] = (f4v){0.f, 0.f, 0.f, 0.f};
  }

  // ---------------- layer 1: h = relu(x @ W1 + b1), K padded to 416 --------
  for (int kk = 0; kk < NK1; ++kk) {
    const s8v* src = (const s8v*)(W1sw + (size_t)kk * CHUNK);
    s8v w0 = src[tid], w1 = src[tid + NT], w2 = src[tid + 2 * NT];

    s8v a0, a1;
    if (kk < NK1 - 1) {                       // k = kk*32 + quad*8 + j, all < 384
      const float* p0 = x + xr0 + kk * 32 + quad * 8;
      const float* p1 = x + xr1 + kk * 32 + quad * 8;
      f4a v00 = *(const f4a*)p0, v01 = *(const f4a*)(p0 + 4);
      f4a v10 = *(const f4a*)p1, v11 = *(const f4a*)(p1 + 4);
      #pragma unroll
      for (int j = 0; j < 4; ++j) {
        a0[j]     = (short)f2bf(v00[j]);
        a0[j + 4] = (short)f2bf(v01[j]);
        a1[j]     = (short)f2bf(v10[j]);
        a1[j + 4] = (short)f2bf(v11[j]);
      }
    } else {                                  // only k==384 valid (quad 0, j 0)
      float v0 = (quad == 0) ? x[xr0 + 384] : 0.f;
      float v1 = (quad == 0) ? x[xr1 + 384] : 0.f;
      a0 = (s8v){0,0,0,0,0,0,0,0};
      a1 = (s8v){0,0,0,0,0,0,0,0};
      a0[0] = (short)f2bf(v0);
      a1[0] = (short)f2bf(v1);
    }

    ((s8v*)bS)[tid] = w0;
    ((s8v*)bS)[tid + NT] = w1;
    ((s8v*)bS)[tid + 2 * NT] = w2;
    __syncthreads();

    #pragma unroll
    for (int t = 0; t < 6; ++t) {
      s8v b = *(const s8v*)&bS[((ch * 6 + t) * 64 + lane) * 8];
      acc0[t] = __builtin_amdgcn_mfma_f32_16x16x32_bf16(a0, b, acc0[t], 0, 0, 0);
      acc1[t] = __builtin_amdgcn_mfma_f32_16x16x32_bf16(a1, b, acc1[t], 0, 0, 0);
    }
    __syncthreads();
  }

  // epilogue 1: bias + relu, h -> LDS bf16 row-major
  #pragma unroll
  for (int t = 0; t < 6; ++t) {
    int c = ch * 96 + t * 16 + m;
    float bb = b1[c];
    #pragma unroll
    for (int r4 = 0; r4 < 4; ++r4) {
      int r = rh * 32 + quad * 4 + r4;
      float v0 = acc0[t][r4] + bb; v0 = v0 > 0.f ? v0 : 0.f;
      hS[r * H2 + c] = f2bf(v0);
      float v1 = acc1[t][r4] + bb; v1 = v1 > 0.f ? v1 : 0.f;
      hS[(r + 16) * H2 + c] = f2bf(v1);
      acc0[t][r4] = 0.f;
      acc1[t][r4] = 0.f;
    }
  }

  // ---------------- layer 2: feat = relu(h @ W2 + b2) ----------------------
  const int ar0 = (rh * 32 + m) * H2;
  for (int kk = 0; kk < NK2; ++kk) {
    const s8v* src = (const s8v*)(W2sw + (size_t)kk * CHUNK);
    s8v w0 = src[tid], w1 = src[tid + NT], w2 = src[tid + 2 * NT];
    ((s8v*)bS)[tid] = w0;
    ((s8v*)bS)[tid + NT] = w1;
    ((s8v*)bS)[tid + 2 * NT] = w2;
    __syncthreads();                          // fences epilogue-1 hS writes too

    s8v a0 = *(const s8v*)&hS[ar0 + kk * 32 + quad * 8];
    s8v a1 = *(const s8v*)&hS[ar0 + 16 * H2 + kk * 32 + quad * 8];
    #pragma unroll
    for (int t = 0; t < 6; ++t) {
      s8v b = *(const s8v*)&bS[((ch * 6 + t) * 64 + lane) * 8];
      acc0[t] = __builtin_amdgcn_mfma_f32_16x16x32_bf16(a0, b, acc0[t], 0, 0, 0);
      acc1[t] = __builtin_amdgcn_mfma_f32_16x16x32_bf16(a1, b, acc1[t], 0, 0, 0);
    }
    __syncthreads();
  }

  // epilogue 2: bias + relu, feat (bf16) overwrites h region
  #pragma unroll
  for (int t = 0; t < 6; ++t) {
    int c = ch * 96 + t * 16 + m;
    float bb = b2[c];
    #pragma unroll
    for (int r4 = 0; r4 < 4; ++r4) {
      int r = rh * 32 + quad * 4 + r4;
      float v0 = acc0[t][r4] + bb;
      hS[r * H2 + c] = f2bf(v0 > 0.f ? v0 : 0.f);
      float v1 = acc1[t][r4] + bb;
      hS[(r + 16) * H2 + c] = f2bf(v1 > 0.f ? v1 : 0.f);
    }
  }
  __syncthreads();

  // ---------------- routed head (fp32 weights, bf16 feat) ------------------
  const int cls = lane >> 2, qp = lane & 3;   // 16 classes x 4 k-quarters
  #pragma unroll 2
  for (int rr = 0; rr < 16; ++rr) {
    int row = wid * 16 + rr;
    int hidx = idxS[row];
    int g = permS[row];
    const float4* wp = (const float4*)(Wh + ((size_t)hidx * kC + cls) * kDh + qp * 48);
    const unsigned short* fr = &hS[row * H2 + qp * 48];
    float s = 0.f;
    #pragma unroll
    for (int t = 0; t < 6; ++t) {
      s8v f8 = *(const s8v*)&fr[t * 8];
      float4 wA = wp[2 * t], wB = wp[2 * t + 1];
      s += wA.x * bf2f(f8[0]) + wA.y * bf2f(f8[1]) +
           wA.z * bf2f(f8[2]) + wA.w * bf2f(f8[3]);
      s += wB.x * bf2f(f8[4]) + wB.y * bf2f(f8[5]) +
           wB.z * bf2f(f8[6]) + wB.w * bf2f(f8[7]);
    }
    s += __shfl_xor(s, 1);
    s += __shfl_xor(s, 2);
    if (qp == 0)
      out[(size_t)g * kC + cls] = s + bh[(size_t)hidx * kC + cls];
  }
}

extern "C" void kernel_launch(void* const* d_in, const int* in_sizes, int n_in,
                              void* d_out, int out_size, void* d_ws, size_t ws_size,
                              hipStream_t stream) {
  const float* x  = (const float*)d_in[0];
  const int*   qd = (const int*)  d_in[1];
  const int*   ic = (const int*)  d_in[2];
  const float* W1 = (const float*)d_in[3];
  const float* b1 = (const float*)d_in[4];
  const float* W2 = (const float*)d_in[5];
  const float* b2 = (const float*)d_in[6];
  const float* Wh = (const float*)d_in[7];
  const float* bh = (const float*)d_in[8];
  float* out = (float*)d_out;

  char* ws = (char*)d_ws;
  unsigned short* W1sw = (unsigned short*)(ws + WS_W1);
  unsigned short* W2sw = (unsigned short*)(ws + WS_W2);
  int* hist   = (int*)(ws + WS_HIST);
  int* cursor = (int*)(ws + WS_CUR);
  int* perm   = (int*)(ws + WS_PERM);

  int B = in_sizes[1];   // 131072

  zero_hist<<<2, 1024, 0, stream>>>(hist);
  hist_k<<<(B + 255) / 256, 256, 0, stream>>>(qd, ic, B, hist);
  scan_k<<<1, 1024, 0, stream>>>(hist, cursor);
  scatter_k<<<(B + 255) / 256, 256, 0, stream>>>(qd, ic, B, cursor, perm);

  prep_swizzle<<<(NK1 * CHUNK + 255) / 256, 256, 0, stream>>>(W1, kDin, NK1, W1sw);
  prep_swizzle<<<(NK2 * CHUNK + 255) / 256, 256, 0, stream>>>(W2, kDh,  NK2, W2sw);

  fused_qmlp3<<<B / BM, NT, 0, stream>>>(x, qd, ic, b1, b2, Wh, bh,
                                         W1sw, W2sw, perm, out);
}